// Round 9
// baseline (210.797 us; speedup 1.0000x reference)
//
#include <hip/hip_runtime.h>
#include <stdint.h>
#include <math.h>

#define B_SZ 4
#define S_LEN 2048
#define NH 16
#define HD 64
#define DM 1024
#define M_ROWS (B_SZ * S_LEN)  // 8192
#define NQ 16                  // q-tiles of 128

typedef __bf16 bf16x8 __attribute__((ext_vector_type(8)));
typedef __bf16 bf16x4 __attribute__((ext_vector_type(4)));
typedef float f32x4 __attribute__((ext_vector_type(4)));
typedef unsigned int u32x2 __attribute__((ext_vector_type(2)));

typedef __attribute__((address_space(3))) void lds_t;
typedef __attribute__((address_space(1))) const void gbl_t;

__device__ __forceinline__ unsigned cvtpk_bf16(float a, float b) {
  unsigned r;
  asm("v_cvt_pk_bf16_f32 %0, %1, %2" : "=v"(r) : "v"(a), "v"(b));
  return r;
}

// ---------------- fp32 -> bf16 converts ----------------
__global__ void cvt_f32_bf16(const float* __restrict__ in,
                             __bf16* __restrict__ out, int n4) {
  int i = blockIdx.x * blockDim.x + threadIdx.x;
  int stride = gridDim.x * blockDim.x;
  for (; i < n4; i += stride) {
    f32x4 v = reinterpret_cast<const f32x4*>(in)[i];
    bf16x4 o;
    o[0] = (__bf16)v[0]; o[1] = (__bf16)v[1];
    o[2] = (__bf16)v[2]; o[3] = (__bf16)v[3];
    reinterpret_cast<bf16x4*>(out)[i] = o;
  }
}

__global__ void cvt_weights(const float* __restrict__ wq, const float* __restrict__ wk,
                            const float* __restrict__ wv, const float* __restrict__ wo,
                            __bf16* __restrict__ dst) {
  const int N4 = DM * DM / 4;
  int i = blockIdx.x * blockDim.x + threadIdx.x;
  int stride = gridDim.x * blockDim.x;
  for (; i < 4 * N4; i += stride) {
    int sel = i >> 18;
    const float* src = (sel == 0) ? wq : (sel == 1) ? wk : (sel == 2) ? wv : wo;
    f32x4 v = reinterpret_cast<const f32x4*>(src)[i & (N4 - 1)];
    bf16x4 o;
    o[0] = (__bf16)v[0]; o[1] = (__bf16)v[1];
    o[2] = (__bf16)v[2]; o[3] = (__bf16)v[3];
    reinterpret_cast<bf16x4*>(dst)[i] = o;
  }
}

// ============ QKV GEMM: 256x128 tile, 8 waves, phase-interleaved ============
// C = A[8192,1024] @ BT[3072,1024]^T. Epilogue routes Q*0.125/K/V^T.
// LDS: 2 buffers x (A 32KB + B 16KB) = 96KB. 4 phases/K-tile, counted vmcnt.
__global__ __launch_bounds__(512, 2) void gemm256_qkv(
    const unsigned short* __restrict__ A, const unsigned short* __restrict__ BT,
    __bf16* __restrict__ Qb, __bf16* __restrict__ Kb, __bf16* __restrict__ Vt) {
  __shared__ __align__(16) uint8_t L[2][49152];  // [buf][A 32768 | B 16384]

  const int t = threadIdx.x, lane = t & 63;
  const int wid = t >> 6;
  const int wm = wid >> 1, wn = wid & 1;   // 4M x 2N waves
  const int g = lane >> 4, c = lane & 15;

  // XCD-bijective swizzle (768 % 8 == 0)
  const int bid = (int)blockIdx.x;
  const int wg = (bid & 7) * 96 + (bid >> 3);
  const int bx = wg % 24, by = wg / 24;
  const int tm0 = by * 256, tn0 = bx * 128;
  const int K = DM;

  // staging maps: unit = stripes of 32 rows every 64 (matches phase reads)
  const int u0 = t >> 3;                 // 0..63
  const int colswz = ((t & 7) << 4) ^ ((u0 & 7) << 4);
  const uint8_t* Ag = (const uint8_t*)A;
  const uint8_t* Bg = (const uint8_t*)BT;

  // A unit h, load l: rows stripe=(u0>>5)+2l -> R = stripe*64 + h*32 + (u0&31)
  const int arow0 = (u0 >> 5) * 64 + (u0 & 31);
  // dest: L[buf] + h*16384 + l*8192 + t*16
#define STAGE_A(buf_, h_, kb_) do {                                            \
    const uint8_t* s0 = Ag + ((size_t)(tm0 + arow0 + (h_) * 32) * K) * 2 +     \
                        (kb_) * 128 + colswz;                                  \
    uint8_t* d = &L[buf_][0] + (h_) * 16384 + t * 16;                          \
    __builtin_amdgcn_global_load_lds((gbl_t*)s0, (lds_t*)d, 16, 0, 0);         \
    __builtin_amdgcn_global_load_lds((gbl_t*)(s0 + (size_t)128 * K * 2),       \
                                     (lds_t*)(d + 8192), 16, 0, 0);            \
  } while (0)
  // B unit h: 64 rows, 1 load: R = (u0>>5)*64 + h*32 + (u0&31)
#define STAGE_B(buf_, h_, kb_) do {                                            \
    const uint8_t* s0 = Bg + ((size_t)(tn0 + arow0 + (h_) * 32) * K) * 2 +     \
                        (kb_) * 128 + colswz;                                  \
    uint8_t* d = &L[buf_][0] + 32768 + (h_) * 8192 + t * 16;                   \
    __builtin_amdgcn_global_load_lds((gbl_t*)s0, (lds_t*)d, 16, 0, 0);         \
  } while (0)

  const int kxor = (c & 7) << 4;
  f32x4 acc[4][4] = {};

  // prologue: tile 0 fully staged
  STAGE_A(0, 0, 0); STAGE_A(0, 1, 0);
  STAGE_B(0, 0, 0); STAGE_B(0, 1, 0);
  asm volatile("s_waitcnt vmcnt(0)" ::: "memory");
  asm volatile("s_barrier" ::: "memory");

  // phase body: reads a[MH*2+i], b[NH*2+j] from buf, 8 MFMA
#define PHASE(buf_, MH, NH, WAITSTR, ISSUE) do {                               \
    const uint8_t* Ab = &L[buf_][0];                                           \
    const uint8_t* Bb = &L[buf_][0] + 32768;                                   \
    bf16x8 af[2][2], bf[2][2];                                                 \
    _Pragma("unroll") for (int i = 0; i < 2; ++i) {                            \
      const int mf = MH * 2 + i;                                               \
      const int r = (mf >> 1) * 16384 + (wm * 32 + (mf & 1) * 16 + c) * 128;   \
      af[i][0] = *reinterpret_cast<const bf16x8*>(Ab + r + ((g * 16) ^ kxor)); \
      af[i][1] = *reinterpret_cast<const bf16x8*>(Ab + r + ((64 + g * 16) ^ kxor)); \
    }                                                                          \
    _Pragma("unroll") for (int j = 0; j < 2; ++j) {                            \
      const int nf = NH * 2 + j;                                               \
      const int r = (nf >> 1) * 8192 + (wn * 32 + (nf & 1) * 16 + c) * 128;    \
      bf[j][0] = *reinterpret_cast<const bf16x8*>(Bb + r + ((g * 16) ^ kxor)); \
      bf[j][1] = *reinterpret_cast<const bf16x8*>(Bb + r + ((64 + g * 16) ^ kxor)); \
    }                                                                          \
    WAITSTR;                                                                   \
    ISSUE;                                                                     \
    asm volatile("s_barrier" ::: "memory");                                    \
    __builtin_amdgcn_s_setprio(1);                                            \
    _Pragma("unroll") for (int i = 0; i < 2; ++i)                              \
      _Pragma("unroll") for (int j = 0; j < 2; ++j) {                          \
        acc[MH * 2 + i][NH * 2 + j] = __builtin_amdgcn_mfma_f32_16x16x32_bf16( \
            af[i][0], bf[j][0], acc[MH * 2 + i][NH * 2 + j], 0, 0, 0);         \
        acc[MH * 2 + i][NH * 2 + j] = __builtin_amdgcn_mfma_f32_16x16x32_bf16( \
            af[i][1], bf[j][1], acc[MH * 2 + i][NH * 2 + j], 0, 0, 0);         \
      }                                                                        \
    __builtin_amdgcn_s_setprio(0);                                            \
    asm volatile("s_barrier" ::: "memory");                                    \
  } while (0)

  const int NT = K / 64;  // 16
  for (int kb = 0; kb < NT; ++kb) {
    const int cur = kb & 1;
    const int nxt = cur ^ 1;
    const int kn = (kb + 1 < NT) ? (kb + 1) : (NT - 1);  // clamped (uniform issue)
    const int kc = kn * 128;  // col-byte base of next tile

    // Ph0 (Mh0 x Nh0): ensure B1(cur) landed for Ph1; issue A0'(kn)
    PHASE(cur, 0, 0,
          asm volatile("s_waitcnt vmcnt(2)" ::: "memory"),
          STAGE_A(nxt, 0, kn));
    // Ph1 (Mh0 x Nh1): ensure A1(cur) landed for Ph2; issue B0',B1'
    PHASE(cur, 0, 1,
          asm volatile("s_waitcnt vmcnt(2)" ::: "memory"),
          do { STAGE_B(nxt, 0, kn); STAGE_B(nxt, 1, kn); } while (0));
    // Ph2 (Mh1 x Nh0): no wait; issue A1'
    PHASE(cur, 1, 0, (void)0, STAGE_A(nxt, 1, kn));
    // Ph3 (Mh1 x Nh1): ensure A0',B0' landed for next tile's Ph0
    PHASE(cur, 1, 1,
          asm volatile("s_waitcnt vmcnt(3)" ::: "memory"),
          (void)0);
    (void)kc;
  }
  asm volatile("s_waitcnt vmcnt(0)" ::: "memory");
#undef PHASE
#undef STAGE_A
#undef STAGE_B

  // epilogue: route Q (*0.125) / K / V^T
  const int rm0 = tm0 + wm * 64;
  const int cn0 = tn0 + wn * 64;
  const int sel = tn0 >> 10;  // uniform per block (128 | 1024)
#pragma unroll
  for (int mf = 0; mf < 4; ++mf) {
#pragma unroll
    for (int nf = 0; nf < 4; ++nf) {
      f32x4 v = acc[mf][nf];
#pragma unroll
      for (int j = 0; j < 4; ++j) {
        int rm = rm0 + mf * 16 + g * 4 + j;
        int cn = cn0 + nf * 16 + c;
        int b = rm >> 11, s = rm & 2047;
        int dmn = cn & 1023;
        int h = dmn >> 6, d = dmn & 63;
        float val = v[j];
        if (sel == 0) {
          Qb[(((size_t)(b * NH + h) * S_LEN + s) << 6) + d] = (__bf16)(val * 0.125f);
        } else if (sel == 1) {
          Kb[(((size_t)(b * NH + h) * S_LEN + s) << 6) + d] = (__bf16)val;
        } else {
          Vt[((size_t)(b * NH + h) * HD + d) * S_LEN + s] = (__bf16)val;
        }
      }
    }
  }
}

// ---------------- O-proj GEMM, 128x128, BK=64, swizzled LDS ----------------
__global__ __launch_bounds__(256, 2) void gemm64_o(
    const unsigned short* __restrict__ A, const unsigned short* __restrict__ BT,
    float* __restrict__ Out) {
  __shared__ __align__(16) unsigned short As[128 * 64];
  __shared__ __align__(16) unsigned short Bs[128 * 64];

  const int t = threadIdx.x, lane = t & 63, w = t >> 6;
  const int wm = w >> 1, wn = w & 1;
  const int g = lane >> 4, c = lane & 15;
  const int NX = DM / 128;

  const int nwg = (int)gridDim.x;
  const int cpx = nwg >> 3;
  const int bid = (int)blockIdx.x;
  const int wg = (bid & 7) * cpx + (bid >> 3);
  const int bx = wg % NX, by = wg / NX;
  const int tm0 = by * 128, tn0 = bx * 128;
  const int K = DM;

  const int srow = t >> 3;
  const int scolb = (t & 7) << 4;
  const int ssw = scolb ^ ((srow & 7) << 4);
  const uint8_t* gA0 = (const uint8_t*)A + ((size_t)(tm0 + srow) * K) * 2 + ssw;
  const uint8_t* gB0 = (const uint8_t*)BT + ((size_t)(tn0 + srow) * K) * 2 + ssw;
  uint8_t* lA0 = (uint8_t*)As + t * 16;
  uint8_t* lB0 = (uint8_t*)Bs + t * 16;
  const int kxor = (c & 7) << 4;

  f32x4 acc[4][4] = {};

  for (int k0 = 0; k0 < K; k0 += 64) {
#pragma unroll
    for (int q = 0; q < 4; ++q) {
      __builtin_amdgcn_global_load_lds((gbl_t*)(gA0 + ((size_t)q * 32 * K + k0) * 2),
                                       (lds_t*)(lA0 + q * 4096), 16, 0, 0);
      __builtin_amdgcn_global_load_lds((gbl_t*)(gB0 + ((size_t)q * 32 * K + k0) * 2),
                                       (lds_t*)(lB0 + q * 4096), 16, 0, 0);
    }
    __syncthreads();

#pragma unroll
    for (int ks = 0; ks < 2; ++ks) {
      bf16x8 af[4], bfm[4];
#pragma unroll
      for (int mb = 0; mb < 4; ++mb)
        af[mb] = *reinterpret_cast<const bf16x8*>(
            (const uint8_t*)As + (wm * 64 + mb * 16 + c) * 128 + ((ks * 64 + g * 16) ^ kxor));
#pragma unroll
      for (int nb = 0; nb < 4; ++nb)
        bfm[nb] = *reinterpret_cast<const bf16x8*>(
            (const uint8_t*)Bs + (wn * 64 + nb * 16 + c) * 128 + ((ks * 64 + g * 16) ^ kxor));
#pragma unroll
      for (int mb = 0; mb < 4; ++mb)
#pragma unroll
        for (int nb = 0; nb < 4; ++nb)
          acc[mb][nb] = __builtin_amdgcn_mfma_f32_16x16x32_bf16(af[mb], bfm[nb], acc[mb][nb], 0, 0, 0);
    }
    __syncthreads();
  }

  const int rm0 = tm0 + wm * 64;
  const int cn0 = tn0 + wn * 64;
#pragma unroll
  for (int mb = 0; mb < 4; ++mb)
#pragma unroll
    for (int nb = 0; nb < 4; ++nb) {
      f32x4 v = acc[mb][nb];
#pragma unroll
      for (int j = 0; j < 4; ++j) {
        int rm = rm0 + mb * 16 + g * 4 + j;
        int cn = cn0 + nb * 16 + c;
        Out[(size_t)rm * DM + cn] = v[j];
      }
    }
}

// ---------------- flash attention (causal, no-max softmax, KV-split) ----------
template <int SPLIT>
__global__ __launch_bounds__(256, 3) void attn_kernel(
    const unsigned short* __restrict__ Qb, const unsigned short* __restrict__ Kb,
    const unsigned short* __restrict__ Vt, __bf16* __restrict__ Aout,
    __bf16* __restrict__ AP, float* __restrict__ Lp) {
  __shared__ __align__(16) unsigned short KVs[2][8192];   // 32KB
  __shared__ __align__(16) unsigned short Ps[4][32 * 72]; // per-wave P, 18KB

  const int t = threadIdx.x, lane = t & 63, w = t >> 6;
  const int g = lane >> 4, c = lane & 15;
  const int bh = blockIdx.y;
  const int qx = (NQ - 1) - (int)blockIdx.x / SPLIT;
  const int sp = (int)blockIdx.x % SPLIT;
  const int b = bh >> 4, h = bh & 15;
  const int q0 = qx * 128 + w * 32;

  const unsigned short* Qp = Qb + (size_t)bh * S_LEN * HD;
  const uint8_t* Kg8 = (const uint8_t*)(Kb + (size_t)bh * S_LEN * HD);
  const uint8_t* Vg8 = (const uint8_t*)(Vt + (size_t)bh * HD * S_LEN);

  const int sr = t >> 3;
  const int scb = ((t & 7) << 4) ^ ((sr & 7) << 4);
  const uint8_t* Kst = Kg8 + (size_t)sr * 128 + scb;
  const uint8_t* Vst = Vg8 + (size_t)sr * (S_LEN * 2) + scb;
  uint8_t* Ls = (uint8_t*)&KVs[0][0];

#define STAGE(buf, kvb_) do {                                                  \
    uint8_t* kd = Ls + (buf) * 16384 + t * 16;                                 \
    const uint8_t* kg = Kst + (size_t)(kvb_) * 128;                            \
    const uint8_t* vg = Vst + (size_t)(kvb_) * 2;                              \
    __builtin_amdgcn_global_load_lds((gbl_t*)kg, (lds_t*)kd, 16, 0, 0);        \
    __builtin_amdgcn_global_load_lds((gbl_t*)(kg + 32 * 128),                  \
                                     (lds_t*)(kd + 4096), 16, 0, 0);           \
    __builtin_amdgcn_global_load_lds((gbl_t*)vg, (lds_t*)(kd + 8192), 16, 0, 0);\
    __builtin_amdgcn_global_load_lds((gbl_t*)(vg + (size_t)32 * S_LEN * 2),    \
                                     (lds_t*)(kd + 12288), 16, 0, 0);          \
  } while (0)

  bf16x8 qf[2][2];
#pragma unroll
  for (int mb = 0; mb < 2; ++mb)
#pragma unroll
    for (int ks = 0; ks < 2; ++ks)
      qf[mb][ks] = *reinterpret_cast<const bf16x8*>(
          Qp + (size_t)(q0 + mb * 16 + c) * HD + ks * 32 + g * 8);

  bf16x8 onesf;
#pragma unroll
  for (int i = 0; i < 8; ++i) onesf[i] = (__bf16)1.0f;

  f32x4 oacc[2][4] = {};
  f32x4 lacc[2] = {};

  const int kxor = (c & 7) << 4;
  const int n_total = 2 * qx + 2;
  const int chunk = (n_total + SPLIT - 1) / SPLIT;
  int t0 = sp * chunk; if (t0 > n_total) t0 = n_total;
  int t1 = t0 + chunk; if (t1 > n_total) t1 = n_total;
  const int nblk_w = (q0 >> 6) + 1;

  const int st0 = (t0 < n_total) ? t0 : (n_total - 1);
  STAGE(0, st0 * 64);
  __syncthreads();

  __bf16* psw = (__bf16*)&Ps[w][0];
  const int qr = q0 + c;

  for (int kb = t0; kb < t1; ++kb) {
    const int cur = (kb - t0) & 1;
    if (kb + 1 < t1) STAGE(cur ^ 1, (kb + 1) * 64);

    if (kb < nblk_w) {
      const int kvb = kb * 64;
      const uint8_t* KL = Ls + cur * 16384;
      const uint8_t* VL = KL + 8192;

      f32x4 sacc[2][4] = {};
      __builtin_amdgcn_s_setprio(1);
#pragma unroll
      for (int ks = 0; ks < 2; ++ks) {
#pragma unroll
        for (int nb = 0; nb < 4; ++nb) {
          bf16x8 kf = *reinterpret_cast<const bf16x8*>(
              KL + (nb * 16 + c) * 128 + ((ks * 64 + g * 16) ^ kxor));
          sacc[0][nb] = __builtin_amdgcn_mfma_f32_16x16x32_bf16(kf, qf[0][ks], sacc[0][nb], 0, 0, 0);
          sacc[1][nb] = __builtin_amdgcn_mfma_f32_16x16x32_bf16(kf, qf[1][ks], sacc[1][nb], 0, 0, 0);
        }
      }
      __builtin_amdgcn_s_setprio(0);

      if (kb == nblk_w - 1) {
#pragma unroll
        for (int mb = 0; mb < 2; ++mb) {
          const int qrm = qr + mb * 16;
#pragma unroll
          for (int nb = 0; nb < 4; ++nb) {
            const int key0 = kvb + nb * 16 + g * 4;
            float p0 = (key0 + 0 <= qrm) ? __expf(sacc[mb][nb][0]) : 0.f;
            float p1 = (key0 + 1 <= qrm) ? __expf(sacc[mb][nb][1]) : 0.f;
            float p2 = (key0 + 2 <= qrm) ? __expf(sacc[mb][nb][2]) : 0.f;
            float p3 = (key0 + 3 <= qrm) ? __expf(sacc[mb][nb][3]) : 0.f;
            u32x2 pk = {cvtpk_bf16(p0, p1), cvtpk_bf16(p2, p3)};
            *reinterpret_cast<u32x2*>(psw + (mb * 16 + c) * 72 + nb * 16 + g * 4) = pk;
          }
        }
      } else {
#pragma unroll
        for (int mb = 0; mb < 2; ++mb)
#pragma unroll
          for (int nb = 0; nb < 4; ++nb) {
            float p0 = __expf(sacc[mb][nb][0]);
            float p1 = __expf(sacc[mb][nb][1]);
            float p2 = __expf(sacc[mb][nb][2]);
            float p3 = __expf(sacc[mb][nb][3]);
            u32x2 pk = {cvtpk_bf16(p0, p1), cvtpk_bf16(p2, p3)};
            *reinterpret_cast<u32x2*>(psw + (mb * 16 + c) * 72 + nb * 16 + g * 4) = pk;
          }
      }

      bf16x8 pf0_0 = *reinterpret_cast<const bf16x8*>(psw + (c) * 72 + g * 8);
      bf16x8 pf0_1 = *reinterpret_cast<const bf16x8*>(psw + (c) * 72 + 32 + g * 8);
      bf16x8 pf1_0 = *reinterpret_cast<const bf16x8*>(psw + (16 + c) * 72 + g * 8);
      bf16x8 pf1_1 = *reinterpret_cast<const bf16x8*>(psw + (16 + c) * 72 + 32 + g * 8);

      __builtin_amdgcn_s_setprio(1);
      lacc[0] = __builtin_amdgcn_mfma_f32_16x16x32_bf16(pf0_0, onesf, lacc[0], 0, 0, 0);
      lacc[0] = __builtin_amdgcn_mfma_f32_16x16x32_bf16(pf0_1, onesf, lacc[0], 0, 0, 0);
      lacc[1] = __builtin_amdgcn_mfma_f32_16x16x32_bf16(pf1_0, onesf, lacc[1], 0, 0, 0);
      lacc[1] = __builtin_amdgcn_mfma_f32_16x16x32_bf16(pf1_1, onesf, lacc[1], 0, 0, 0);

#pragma unroll
      for (int db = 0; db < 4; ++db) {
        bf16x8 vf0 = *reinterpret_cast<const bf16x8*>(
            VL + (db * 16 + c) * 128 + ((g * 16) ^ kxor));
        bf16x8 vf1 = *reinterpret_cast<const bf16x8*>(
            VL + (db * 16 + c) * 128 + ((64 + g * 16) ^ kxor));
        oacc[0][db] = __builtin_amdgcn_mfma_f32_16x16x32_bf16(pf0_0, vf0, oacc[0][db], 0, 0, 0);
        oacc[0][db] = __builtin_amdgcn_mfma_f32_16x16x32_bf16(pf0_1, vf1, oacc[0][db], 0, 0, 0);
        oacc[1][db] = __builtin_amdgcn_mfma_f32_16x16x32_bf16(pf1_0, vf0, oacc[1][db], 0, 0, 0);
        oacc[1][db] = __builtin_amdgcn_mfma_f32_16x16x32_bf16(pf1_1, vf1, oacc[1][db], 0, 0, 0);
      }
      __builtin_amdgcn_s_setprio(0);
    }
    __syncthreads();
  }
#undef STAGE

  if (SPLIT == 1) {
    float rl[2][4];
#pragma unroll
    for (int mb = 0; mb < 2; ++mb)
#pragma unroll
      for (int j = 0; j < 4; ++j) rl[mb][j] = 1.0f / lacc[mb][j];
#pragma unroll
    for (int mb = 0; mb < 2; ++mb)
#pragma unroll
      for (int db = 0; db < 4; ++db)
#pragma unroll
        for (int j = 0; j < 4; ++j) {
          float o = oacc[mb][db][j] * rl[mb][j];
          int s = q0 + mb * 16 + g * 4 + j;
          int d = db * 16 + c;
          Aout[(size_t)(b * S_LEN + s) * DM + h * HD + d] = (__bf16)o;
        }
  } else {
    __bf16* APs = AP + (size_t)(sp * (B_SZ * NH) + bh) * S_LEN * HD;
    float* Lps = Lp + (size_t)(sp * (B_SZ * NH) + bh) * S_LEN;
#pragma unroll
    for (int mb = 0; mb < 2; ++mb) {
#pragma unroll
      for (int db = 0; db < 4; ++db)
#pragma unroll
        for (int j = 0; j < 4; ++j) {
          int q = q0 + mb * 16 + g * 4 + j;
          APs[(size_t)q * HD + db * 16 + c] = (__bf16)oacc[mb][db][j];
        }
      if (c == 0) {
#pragma unroll
        for (int j = 0; j < 4; ++j)
          Lps[q0 + mb * 16 + g * 4 + j] = lacc[mb][j];
      }
    }
  }
}

// combine: Aout = (ΣAP)/(ΣL), bf16 [B*S, 1024]
__global__ void attn_combine4(const __bf16* __restrict__ AP, const float* __restrict__ Lp,
                              __bf16* __restrict__ Aout) {
  const int NIT = B_SZ * NH * S_LEN * (HD / 8);
  int i = blockIdx.x * blockDim.x + threadIdx.x;
  int stride = gridDim.x * blockDim.x;
  const size_t SOFF = (size_t)(B_SZ * NH) * S_LEN * HD;
  const size_t LOFF = (size_t)(B_SZ * NH) * S_LEN;
  for (; i < NIT; i += stride) {
    int d8 = i & 7;
    int q = (i >> 3) & (S_LEN - 1);
    int bh = i >> 14;
    size_t base = ((size_t)bh * S_LEN + q) * HD + d8 * 8;
    size_t lbase = (size_t)bh * S_LEN + q;
    float l = Lp[lbase] + Lp[LOFF + lbase] + Lp[2 * LOFF + lbase] + Lp[3 * LOFF + lbase];
    float rl = 1.0f / l;
    bf16x8 a0 = *reinterpret_cast<const bf16x8*>(AP + base);
    bf16x8 a1 = *reinterpret_cast<const bf16x8*>(AP + SOFF + base);
    bf16x8 a2 = *reinterpret_cast<const bf16x8*>(AP + 2 * SOFF + base);
    bf16x8 a3 = *reinterpret_cast<const bf16x8*>(AP + 3 * SOFF + base);
    int b = bh >> 4, h = bh & 15;
    bf16x8 o;
#pragma unroll
    for (int k = 0; k < 8; ++k)
      o[k] = (__bf16)((((float)a0[k] + (float)a1[k]) + ((float)a2[k] + (float)a3[k])) * rl);
    *reinterpret_cast<bf16x8*>(Aout + ((size_t)(b * S_LEN + q)) * DM + h * HD + d8 * 8) = o;
  }
}

// ---------------- launcher ----------------
extern "C" void kernel_launch(void* const* d_in, const int* in_sizes, int n_in,
                              void* d_out, int out_size, void* d_ws, size_t ws_size,
                              hipStream_t stream) {
  const float* x = (const float*)d_in[0];
  const float* wq = (const float*)d_in[1];
  const float* wk = (const float*)d_in[2];
  const float* wv = (const float*)d_in[3];
  const float* wo = (const float*)d_in[4];
  float* out = (float*)d_out;

  uint8_t* ws = (uint8_t*)d_ws;
  const size_t MB = 1024 * 1024;
  unsigned short* xb   = (unsigned short*)(ws);             // 16 MB (reused as Aout)
  unsigned short* wcat = (unsigned short*)(ws + 16 * MB);   // 6 MB; dead after qkv
  unsigned short* wob  = (unsigned short*)(ws + 22 * MB);   // 2 MB
  unsigned short* Qb   = (unsigned short*)(ws + 24 * MB);   // 16 MB
  unsigned short* Kb   = (unsigned short*)(ws + 40 * MB);   // 16 MB
  unsigned short* Vt   = (unsigned short*)(ws + 56 * MB);   // 16 MB
  __bf16* AP           = (__bf16*)(ws + 72 * MB);           // 64 MB (4 split partials)
  float* Lp            = (float*)(ws + 16 * MB);            // 2 MB overlay on dead wcat

  {
    int n4x = (M_ROWS * DM) / 4;
    int blk = (n4x + 255) / 256; if (blk > 2048) blk = 2048;
    cvt_f32_bf16<<<blk, 256, 0, stream>>>(x, (__bf16*)xb, n4x);
    cvt_weights<<<1024, 256, 0, stream>>>(wq, wk, wv, wo, (__bf16*)wcat);
  }

  gemm256_qkv<<<dim3(768), 512, 0, stream>>>(
      xb, wcat, (__bf16*)Qb, (__bf16*)Kb, (__bf16*)Vt);

  __bf16* Aout = (__bf16*)xb;  // x no longer needed
  if (ws_size >= (size_t)136 * MB) {
    attn_kernel<4><<<dim3(NQ * 4, B_SZ * NH), 256, 0, stream>>>(
        Qb, Kb, Vt, Aout, AP, Lp);
    attn_combine4<<<2048, 256, 0, stream>>>(AP, Lp, Aout);
  } else {
    attn_kernel<1><<<dim3(NQ, B_SZ * NH), 256, 0, stream>>>(
        Qb, Kb, Vt, Aout, nullptr, nullptr);
  }

  gemm64_o<<<dim3((DM / 128) * (M_ROWS / 128)), 256, 0, stream>>>(xb, wob, out);
}

// Round 10
// 203.023 us; speedup vs baseline: 1.0383x; 1.0383x over previous
//
#include <hip/hip_runtime.h>
#include <stdint.h>
#include <math.h>

#define B_SZ 4
#define S_LEN 2048
#define NH 16
#define HD 64
#define DM 1024
#define M_ROWS (B_SZ * S_LEN)  // 8192
#define NQ 16                  // q-tiles of 128

typedef __bf16 bf16x8 __attribute__((ext_vector_type(8)));
typedef __bf16 bf16x4 __attribute__((ext_vector_type(4)));
typedef float f32x4 __attribute__((ext_vector_type(4)));
typedef unsigned int u32x2 __attribute__((ext_vector_type(2)));

typedef __attribute__((address_space(3))) void lds_t;
typedef __attribute__((address_space(1))) const void gbl_t;

__device__ __forceinline__ unsigned cvtpk_bf16(float a, float b) {
  unsigned r;
  asm("v_cvt_pk_bf16_f32 %0, %1, %2" : "=v"(r) : "v"(a), "v"(b));
  return r;
}

// ---------------- fp32 -> bf16 convert (x + all 4 weights, one launch) -------
__global__ void cvt_all(const float* __restrict__ x,
                        const float* __restrict__ wq, const float* __restrict__ wk,
                        const float* __restrict__ wv, const float* __restrict__ wo,
                        __bf16* __restrict__ xb, __bf16* __restrict__ wdst) {
  const int NX4 = M_ROWS * DM / 4;      // 2097152
  const int NW4 = DM * DM / 4;          // 262144
  const int TOT = NX4 + 4 * NW4;
  int i = blockIdx.x * blockDim.x + threadIdx.x;
  int stride = gridDim.x * blockDim.x;
  for (; i < TOT; i += stride) {
    const float* src;
    __bf16* dst;
    int idx;
    if (i < NX4) {
      src = x; dst = xb; idx = i;
    } else {
      int j = i - NX4;
      int sel = j >> 18;
      src = (sel == 0) ? wq : (sel == 1) ? wk : (sel == 2) ? wv : wo;
      dst = wdst + (size_t)sel * DM * DM;
      idx = j & (NW4 - 1);
    }
    f32x4 v = reinterpret_cast<const f32x4*>(src)[idx];
    bf16x4 o;
    o[0] = (__bf16)v[0]; o[1] = (__bf16)v[1];
    o[2] = (__bf16)v[2]; o[3] = (__bf16)v[3];
    reinterpret_cast<bf16x4*>(dst)[idx] = o;
  }
}

// ---------------- GEMM, 128x128, BK=64, swizzled LDS, DOUBLE-BUFFERED -------
// T3-minimum 2-phase: issue next tile's stage BEFORE ds_read+MFMA, exactly one
// __syncthreads per K-tile (its vmcnt/lgkmcnt drain provides both hazards' fences).
// MODE 0: QKV epilogue (N=3072): Q*0.125 / K / V^T ; MODE 1: fp32 out [M,1024]
template <int MODE>
__global__ __launch_bounds__(256, 2) void gemm64(
    const unsigned short* __restrict__ A, const unsigned short* __restrict__ BT,
    __bf16* __restrict__ Qb, __bf16* __restrict__ Kb, __bf16* __restrict__ Vt,
    float* __restrict__ Out, int NX) {
  __shared__ __align__(16) unsigned short As[2][128 * 64];  // 2 x 16KB
  __shared__ __align__(16) unsigned short Bs[2][128 * 64];  // 2 x 16KB

  const int t = threadIdx.x, lane = t & 63, w = t >> 6;
  const int wm = w >> 1, wn = w & 1;
  const int g = lane >> 4, c = lane & 15;

  // XCD-bijective swizzle (nwg % 8 == 0)
  const int nwg = (int)gridDim.x;
  const int cpx = nwg >> 3;
  const int bid = (int)blockIdx.x;
  const int wg = (bid & 7) * cpx + (bid >> 3);
  const int bx = wg % NX, by = wg / NX;
  const int tm0 = by * 128, tn0 = bx * 128;
  const int K = DM;

  // staging: linear LDS dest t*16, pre-swizzled global source column
  const int srow = t >> 3;
  const int scolb = (t & 7) << 4;
  const int ssw = scolb ^ ((srow & 7) << 4);
  const uint8_t* gA0 = (const uint8_t*)A + ((size_t)(tm0 + srow) * K) * 2 + ssw;
  const uint8_t* gB0 = (const uint8_t*)BT + ((size_t)(tn0 + srow) * K) * 2 + ssw;
  const int kxor = (c & 7) << 4;

#define STAGE(buf_, k0_) do {                                                  \
    uint8_t* lA = (uint8_t*)&As[buf_][0] + t * 16;                             \
    uint8_t* lB = (uint8_t*)&Bs[buf_][0] + t * 16;                             \
    _Pragma("unroll") for (int q = 0; q < 4; ++q) {                            \
      __builtin_amdgcn_global_load_lds(                                        \
          (gbl_t*)(gA0 + ((size_t)q * 32 * K + (k0_)) * 2),                    \
          (lds_t*)(lA + q * 4096), 16, 0, 0);                                  \
      __builtin_amdgcn_global_load_lds(                                        \
          (gbl_t*)(gB0 + ((size_t)q * 32 * K + (k0_)) * 2),                    \
          (lds_t*)(lB + q * 4096), 16, 0, 0);                                  \
    }                                                                          \
  } while (0)

  f32x4 acc[4][4] = {};

  STAGE(0, 0);
  __syncthreads();

  const int NT = K / 64;  // 16
  for (int kt = 0; kt < NT; ++kt) {
    const int cur = kt & 1;
    if (kt + 1 < NT) STAGE(cur ^ 1, (kt + 1) * 64);  // prefetch hides under compute

#pragma unroll
    for (int ks = 0; ks < 2; ++ks) {
      bf16x8 af[4], bfm[4];
#pragma unroll
      for (int mb = 0; mb < 4; ++mb)
        af[mb] = *reinterpret_cast<const bf16x8*>(
            (const uint8_t*)&As[cur][0] + (wm * 64 + mb * 16 + c) * 128 + ((ks * 64 + g * 16) ^ kxor));
#pragma unroll
      for (int nb = 0; nb < 4; ++nb)
        bfm[nb] = *reinterpret_cast<const bf16x8*>(
            (const uint8_t*)&Bs[cur][0] + (wn * 64 + nb * 16 + c) * 128 + ((ks * 64 + g * 16) ^ kxor));
      __builtin_amdgcn_s_setprio(1);
#pragma unroll
      for (int mb = 0; mb < 4; ++mb)
#pragma unroll
        for (int nb = 0; nb < 4; ++nb)
          acc[mb][nb] = __builtin_amdgcn_mfma_f32_16x16x32_bf16(af[mb], bfm[nb], acc[mb][nb], 0, 0, 0);
      __builtin_amdgcn_s_setprio(0);
    }
    // one barrier per tile: drains vmcnt (next tile landed) and guarantees all
    // waves' ds_reads of buf cur are complete before it is overwritten next iter
    __syncthreads();
  }
#undef STAGE

  const int rm0 = tm0 + wm * 64;
  const int cn0 = tn0 + wn * 64;
  const int sel = tn0 >> 10;
#pragma unroll
  for (int mb = 0; mb < 4; ++mb) {
#pragma unroll
    for (int nb = 0; nb < 4; ++nb) {
      f32x4 v = acc[mb][nb];
#pragma unroll
      for (int j = 0; j < 4; ++j) {
        int rm = rm0 + mb * 16 + g * 4 + j;
        int cn = cn0 + nb * 16 + c;
        float val = v[j];
        if (MODE == 0) {
          int b = rm >> 11, s = rm & 2047;
          int dmn = cn & 1023;
          int h = dmn >> 6, d = dmn & 63;
          if (sel == 0) {
            Qb[(((size_t)(b * NH + h) * S_LEN + s) << 6) + d] = (__bf16)(val * 0.125f);
          } else if (sel == 1) {
            Kb[(((size_t)(b * NH + h) * S_LEN + s) << 6) + d] = (__bf16)val;
          } else {
            Vt[((size_t)(b * NH + h) * HD + d) * S_LEN + s] = (__bf16)val;
          }
        } else {
          Out[(size_t)rm * DM + cn] = val;
        }
      }
    }
  }
}

// ---------------- flash attention (causal, no-max softmax, KV-split) ----------
// grid (NQ*SPLIT, B*H), 256 threads = 4 waves; wave w owns q-rows [q0, q0+32).
// K,V^T staged in LDS (XOR-swizzled via pre-swizzled global src), dbuf.
// SWAPPED QK^T: sacc = mfma(K, Q) -> P written as packed ds_write_b64.
template <int SPLIT>
__global__ __launch_bounds__(256, 3) void attn_kernel(
    const unsigned short* __restrict__ Qb, const unsigned short* __restrict__ Kb,
    const unsigned short* __restrict__ Vt, __bf16* __restrict__ Aout,
    __bf16* __restrict__ AP, float* __restrict__ Lp) {
  __shared__ __align__(16) unsigned short KVs[2][8192];   // 32KB
  __shared__ __align__(16) unsigned short Ps[4][32 * 72]; // per-wave P, 18KB

  const int t = threadIdx.x, lane = t & 63, w = t >> 6;
  const int g = lane >> 4, c = lane & 15;
  const int bh = blockIdx.y;
  const int qx = (NQ - 1) - (int)blockIdx.x / SPLIT;
  const int sp = (int)blockIdx.x % SPLIT;
  const int b = bh >> 4, h = bh & 15;
  const int q0 = qx * 128 + w * 32;

  const unsigned short* Qp = Qb + (size_t)bh * S_LEN * HD;
  const uint8_t* Kg8 = (const uint8_t*)(Kb + (size_t)bh * S_LEN * HD);
  const uint8_t* Vg8 = (const uint8_t*)(Vt + (size_t)bh * HD * S_LEN);

  const int sr = t >> 3;
  const int scb = ((t & 7) << 4) ^ ((sr & 7) << 4);
  const uint8_t* Kst = Kg8 + (size_t)sr * 128 + scb;
  const uint8_t* Vst = Vg8 + (size_t)sr * (S_LEN * 2) + scb;
  uint8_t* Ls = (uint8_t*)&KVs[0][0];

#define STAGE(buf, kvb_) do {                                                  \
    uint8_t* kd = Ls + (buf) * 16384 + t * 16;                                 \
    const uint8_t* kg = Kst + (size_t)(kvb_) * 128;                            \
    const uint8_t* vg = Vst + (size_t)(kvb_) * 2;                              \
    __builtin_amdgcn_global_load_lds((gbl_t*)kg, (lds_t*)kd, 16, 0, 0);        \
    __builtin_amdgcn_global_load_lds((gbl_t*)(kg + 32 * 128),                  \
                                     (lds_t*)(kd + 4096), 16, 0, 0);           \
    __builtin_amdgcn_global_load_lds((gbl_t*)vg, (lds_t*)(kd + 8192), 16, 0, 0);\
    __builtin_amdgcn_global_load_lds((gbl_t*)(vg + (size_t)32 * S_LEN * 2),    \
                                     (lds_t*)(kd + 12288), 16, 0, 0);          \
  } while (0)

  bf16x8 qf[2][2];
#pragma unroll
  for (int mb = 0; mb < 2; ++mb)
#pragma unroll
    for (int ks = 0; ks < 2; ++ks)
      qf[mb][ks] = *reinterpret_cast<const bf16x8*>(
          Qp + (size_t)(q0 + mb * 16 + c) * HD + ks * 32 + g * 8);

  bf16x8 onesf;
#pragma unroll
  for (int i = 0; i < 8; ++i) onesf[i] = (__bf16)1.0f;

  f32x4 oacc[2][4] = {};
  f32x4 lacc[2] = {};

  const int kxor = (c & 7) << 4;
  const int n_total = 2 * qx + 2;
  const int chunk = (n_total + SPLIT - 1) / SPLIT;
  int t0 = sp * chunk; if (t0 > n_total) t0 = n_total;
  int t1 = t0 + chunk; if (t1 > n_total) t1 = n_total;
  const int nblk_w = (q0 >> 6) + 1;

  const int st0 = (t0 < n_total) ? t0 : (n_total - 1);
  STAGE(0, st0 * 64);
  __syncthreads();

  __bf16* psw = (__bf16*)&Ps[w][0];
  const int qr = q0 + c;

  for (int kb = t0; kb < t1; ++kb) {
    const int cur = (kb - t0) & 1;
    if (kb + 1 < t1) STAGE(cur ^ 1, (kb + 1) * 64);

    if (kb < nblk_w) {
      const int kvb = kb * 64;
      const uint8_t* KL = Ls + cur * 16384;
      const uint8_t* VL = KL + 8192;

      f32x4 sacc[2][4] = {};
      __builtin_amdgcn_s_setprio(1);
#pragma unroll
      for (int ks = 0; ks < 2; ++ks) {
#pragma unroll
        for (int nb = 0; nb < 4; ++nb) {
          bf16x8 kf = *reinterpret_cast<const bf16x8*>(
              KL + (nb * 16 + c) * 128 + ((ks * 64 + g * 16) ^ kxor));
          sacc[0][nb] = __builtin_amdgcn_mfma_f32_16x16x32_bf16(kf, qf[0][ks], sacc[0][nb], 0, 0, 0);
          sacc[1][nb] = __builtin_amdgcn_mfma_f32_16x16x32_bf16(kf, qf[1][ks], sacc[1][nb], 0, 0, 0);
        }
      }
      __builtin_amdgcn_s_setprio(0);

      if (kb == nblk_w - 1) {
#pragma unroll
        for (int mb = 0; mb < 2; ++mb) {
          const int qrm = qr + mb * 16;
#pragma unroll
          for (int nb = 0; nb < 4; ++nb) {
            const int key0 = kvb + nb * 16 + g * 4;
            float p0 = (key0 + 0 <= qrm) ? __expf(sacc[mb][nb][0]) : 0.f;
            float p1 = (key0 + 1 <= qrm) ? __expf(sacc[mb][nb][1]) : 0.f;
            float p2 = (key0 + 2 <= qrm) ? __expf(sacc[mb][nb][2]) : 0.f;
            float p3 = (key0 + 3 <= qrm) ? __expf(sacc[mb][nb][3]) : 0.f;
            u32x2 pk = {cvtpk_bf16(p0, p1), cvtpk_bf16(p2, p3)};
            *reinterpret_cast<u32x2*>(psw + (mb * 16 + c) * 72 + nb * 16 + g * 4) = pk;
          }
        }
      } else {
#pragma unroll
        for (int mb = 0; mb < 2; ++mb)
#pragma unroll
          for (int nb = 0; nb < 4; ++nb) {
            float p0 = __expf(sacc[mb][nb][0]);
            float p1 = __expf(sacc[mb][nb][1]);
            float p2 = __expf(sacc[mb][nb][2]);
            float p3 = __expf(sacc[mb][nb][3]);
            u32x2 pk = {cvtpk_bf16(p0, p1), cvtpk_bf16(p2, p3)};
            *reinterpret_cast<u32x2*>(psw + (mb * 16 + c) * 72 + nb * 16 + g * 4) = pk;
          }
      }

      bf16x8 pf0_0 = *reinterpret_cast<const bf16x8*>(psw + (c) * 72 + g * 8);
      bf16x8 pf0_1 = *reinterpret_cast<const bf16x8*>(psw + (c) * 72 + 32 + g * 8);
      bf16x8 pf1_0 = *reinterpret_cast<const bf16x8*>(psw + (16 + c) * 72 + g * 8);
      bf16x8 pf1_1 = *reinterpret_cast<const bf16x8*>(psw + (16 + c) * 72 + 32 + g * 8);

      __builtin_amdgcn_s_setprio(1);
      lacc[0] = __builtin_amdgcn_mfma_f32_16x16x32_bf16(pf0_0, onesf, lacc[0], 0, 0, 0);
      lacc[0] = __builtin_amdgcn_mfma_f32_16x16x32_bf16(pf0_1, onesf, lacc[0], 0, 0, 0);
      lacc[1] = __builtin_amdgcn_mfma_f32_16x16x32_bf16(pf1_0, onesf, lacc[1], 0, 0, 0);
      lacc[1] = __builtin_amdgcn_mfma_f32_16x16x32_bf16(pf1_1, onesf, lacc[1], 0, 0, 0);

#pragma unroll
      for (int db = 0; db < 4; ++db) {
        bf16x8 vf0 = *reinterpret_cast<const bf16x8*>(
            VL + (db * 16 + c) * 128 + ((g * 16) ^ kxor));
        bf16x8 vf1 = *reinterpret_cast<const bf16x8*>(
            VL + (db * 16 + c) * 128 + ((64 + g * 16) ^ kxor));
        oacc[0][db] = __builtin_amdgcn_mfma_f32_16x16x32_bf16(pf0_0, vf0, oacc[0][db], 0, 0, 0);
        oacc[0][db] = __builtin_amdgcn_mfma_f32_16x16x32_bf16(pf0_1, vf1, oacc[0][db], 0, 0, 0);
        oacc[1][db] = __builtin_amdgcn_mfma_f32_16x16x32_bf16(pf1_0, vf0, oacc[1][db], 0, 0, 0);
        oacc[1][db] = __builtin_amdgcn_mfma_f32_16x16x32_bf16(pf1_1, vf1, oacc[1][db], 0, 0, 0);
      }
      __builtin_amdgcn_s_setprio(0);
    }
    __syncthreads();
  }
#undef STAGE

  if (SPLIT == 1) {
    float rl[2][4];
#pragma unroll
    for (int mb = 0; mb < 2; ++mb)
#pragma unroll
      for (int j = 0; j < 4; ++j) rl[mb][j] = 1.0f / lacc[mb][j];
#pragma unroll
    for (int mb = 0; mb < 2; ++mb)
#pragma unroll
      for (int db = 0; db < 4; ++db)
#pragma unroll
        for (int j = 0; j < 4; ++j) {
          float o = oacc[mb][db][j] * rl[mb][j];
          int s = q0 + mb * 16 + g * 4 + j;
          int d = db * 16 + c;
          Aout[(size_t)(b * S_LEN + s) * DM + h * HD + d] = (__bf16)o;
        }
  } else {
    __bf16* APs = AP + (size_t)(sp * (B_SZ * NH) + bh) * S_LEN * HD;
    float* Lps = Lp + (size_t)(sp * (B_SZ * NH) + bh) * S_LEN;
#pragma unroll
    for (int mb = 0; mb < 2; ++mb) {
#pragma unroll
      for (int db = 0; db < 4; ++db)
#pragma unroll
        for (int j = 0; j < 4; ++j) {
          int q = q0 + mb * 16 + g * 4 + j;
          APs[(size_t)q * HD + db * 16 + c] = (__bf16)oacc[mb][db][j];
        }
      if (c == 0) {
#pragma unroll
        for (int j = 0; j < 4; ++j)
          Lps[q0 + mb * 16 + g * 4 + j] = lacc[mb][j];
      }
    }
  }
}

// combine: Aout = (ΣAP)/(ΣL), bf16 [B*S, 1024]
__global__ void attn_combine4(const __bf16* __restrict__ AP, const float* __restrict__ Lp,
                              __bf16* __restrict__ Aout) {
  const int NIT = B_SZ * NH * S_LEN * (HD / 8);
  int i = blockIdx.x * blockDim.x + threadIdx.x;
  int stride = gridDim.x * blockDim.x;
  const size_t SOFF = (size_t)(B_SZ * NH) * S_LEN * HD;
  const size_t LOFF = (size_t)(B_SZ * NH) * S_LEN;
  for (; i < NIT; i += stride) {
    int d8 = i & 7;
    int q = (i >> 3) & (S_LEN - 1);
    int bh = i >> 14;
    size_t base = ((size_t)bh * S_LEN + q) * HD + d8 * 8;
    size_t lbase = (size_t)bh * S_LEN + q;
    float l = Lp[lbase] + Lp[LOFF + lbase] + Lp[2 * LOFF + lbase] + Lp[3 * LOFF + lbase];
    float rl = 1.0f / l;
    bf16x8 a0 = *reinterpret_cast<const bf16x8*>(AP + base);
    bf16x8 a1 = *reinterpret_cast<const bf16x8*>(AP + SOFF + base);
    bf16x8 a2 = *reinterpret_cast<const bf16x8*>(AP + 2 * SOFF + base);
    bf16x8 a3 = *reinterpret_cast<const bf16x8*>(AP + 3 * SOFF + base);
    int b = bh >> 4, h = bh & 15;
    bf16x8 o;
#pragma unroll
    for (int k = 0; k < 8; ++k)
      o[k] = (__bf16)((((float)a0[k] + (float)a1[k]) + ((float)a2[k] + (float)a3[k])) * rl);
    *reinterpret_cast<bf16x8*>(Aout + ((size_t)(b * S_LEN + q)) * DM + h * HD + d8 * 8) = o;
  }
}

// ---------------- launcher ----------------
extern "C" void kernel_launch(void* const* d_in, const int* in_sizes, int n_in,
                              void* d_out, int out_size, void* d_ws, size_t ws_size,
                              hipStream_t stream) {
  const float* x = (const float*)d_in[0];
  const float* wq = (const float*)d_in[1];
  const float* wk = (const float*)d_in[2];
  const float* wv = (const float*)d_in[3];
  const float* wo = (const float*)d_in[4];
  float* out = (float*)d_out;

  uint8_t* ws = (uint8_t*)d_ws;
  const size_t MB = 1024 * 1024;
  unsigned short* xb   = (unsigned short*)(ws);             // 16 MB (reused as Aout)
  unsigned short* wcat = (unsigned short*)(ws + 16 * MB);   // 6 MB; dead after qkv
  unsigned short* wob  = (unsigned short*)(ws + 22 * MB);   // 2 MB
  unsigned short* Qb   = (unsigned short*)(ws + 24 * MB);   // 16 MB
  unsigned short* Kb   = (unsigned short*)(ws + 40 * MB);   // 16 MB
  unsigned short* Vt   = (unsigned short*)(ws + 56 * MB);   // 16 MB
  __bf16* AP           = (__bf16*)(ws + 72 * MB);           // 64 MB (4 split partials)
  float* Lp            = (float*)(ws + 16 * MB);            // 2 MB overlay on dead wcat

  cvt_all<<<2048, 256, 0, stream>>>(x, wq, wk, wv, wo, (__bf16*)xb, (__bf16*)wcat);

  gemm64<0><<<dim3((3 * DM / 128) * (M_ROWS / 128)), 256, 0, stream>>>(
      xb, wcat, (__bf16*)Qb, (__bf16*)Kb, (__bf16*)Vt, nullptr, 3 * DM / 128);

  __bf16* Aout = (__bf16*)xb;  // x no longer needed
  if (ws_size >= (size_t)136 * MB) {
    attn_kernel<4><<<dim3(NQ * 4, B_SZ * NH), 256, 0, stream>>>(
        Qb, Kb, Vt, Aout, AP, Lp);
    attn_combine4<<<2048, 256, 0, stream>>>(AP, Lp, Aout);
  } else {
    attn_kernel<1><<<dim3(NQ, B_SZ * NH), 256, 0, stream>>>(
        Qb, Kb, Vt, Aout, nullptr, nullptr);
  }

  gemm64<1><<<dim3((DM / 128) * (M_ROWS / 128)), 256, 0, stream>>>(
      xb, wob, nullptr, nullptr, nullptr, out, DM / 128);
}